// Round 6
// baseline (677.561 us; speedup 1.0000x reference)
//
#include <hip/hip_runtime.h>

#define DEVINL __device__ __forceinline__

// Problem constants
#define BB 4
#define SS 4096
#define HIDD 1024
#define HH 16
#define DH 64
#define NQKV 3072
#define MM (BB * SS)  // 16384

typedef __attribute__((ext_vector_type(8))) short bf16x8_t;
typedef __attribute__((ext_vector_type(4))) float f32x4_t;

typedef __attribute__((address_space(1))) const void GV;
typedef __attribute__((address_space(3))) void LV;

DEVINL void gload16(const void* g, void* l) {
  // async global->LDS, 16B/lane; LDS dest = wave-uniform base + lane*16
  __builtin_amdgcn_global_load_lds((GV*)g, (LV*)l, 16, 0, 0);
}

DEVINL float bf2f(ushort u) {
  union { unsigned int i; float f; } v;
  v.i = ((unsigned int)u) << 16;
  return v.f;
}
DEVINL ushort f2bf(float f) {
  unsigned int u = __float_as_uint(f);
  u = (u + 0x7fffu + ((u >> 16) & 1u)) >> 16;
  return (ushort)u;
}

// ---------------- fp32 -> bf16 convert (4 elems/thread) ----------------
__global__ __launch_bounds__(256) void k_f2bf(const float* __restrict__ src,
                                              ushort* __restrict__ dst, int n4) {
  int i = blockIdx.x * 256 + threadIdx.x;
  if (i >= n4) return;
  float4 v = ((const float4*)src)[i];
  ushort4 o;
  o.x = f2bf(v.x); o.y = f2bf(v.y); o.z = f2bf(v.z); o.w = f2bf(v.w);
  ((ushort4*)dst)[i] = o;
}

// ---------------- 8-phase 256x256 bf16 GEMM: C = A[M,K] * B[N,K]^T + bias ----
// 8 waves (2M x 4N), BK=64, acc 8x4 frags of 16x16x32. Relaxed barriers:
// no explicit lgkmcnt(0) (compiler emits fine-grained waits); sched_barrier(0)
// only after the counted-vmcnt barriers (RAW fence for freshly staged slots).
template <int MODE>
__global__ __launch_bounds__(512, 2) void k_gemm8p(
    const ushort* __restrict__ A, const ushort* __restrict__ B,
    const float* __restrict__ bias, void* __restrict__ Cv,
    ushort* __restrict__ qT, ushort* __restrict__ vbuf,
    int M, int N, int K) {
  __shared__ ushort As0[256 * 64];
  __shared__ ushort As1[256 * 64];
  __shared__ ushort Bs0[256 * 64];
  __shared__ ushort Bs1[256 * 64];
  __shared__ ushort Dmy[4096];
  const int t = threadIdx.x;
  const int m0 = blockIdx.x * 256, n0 = blockIdx.y * 256;
  const int lane = t & 63, wid = t >> 6;
  const int wm = wid >> 2, wn = wid & 3;   // 2M x 4N waves
  const int fr = lane & 15, g = lane >> 4;
  const int srow = t >> 3;                        // 0..63 (row within 64-row call)
  const int schunk = ((t & 7) ^ (srow & 7)) * 8;  // pre-swizzled 16B chunk
  const int NT = K >> 6;
  const ushort* Ag = A + (size_t)m0 * K;
  const ushort* Bg = B + (size_t)n0 * K;

  f32x4_t acc[8][4] = {};
  bf16x8_t af[2][2], bfr[4][2];

#define STG(ls_, gsrc, tile, hf)                                            \
  {                                                                         \
    if ((tile) < NT) {                                                      \
      const ushort* gs_ = (gsrc) + (size_t)((hf) * 128 + srow) * K +        \
                          (tile) * 64 + schunk;                             \
      ushort* ld_ = (ls_) + ((hf) * 128 + wid * 8) * 64;                    \
      gload16(gs_, ld_);                                                    \
      gload16(gs_ + (size_t)64 * K, ld_ + 64 * 64);                         \
    } else {                                                                \
      const ushort* gs_ = (gsrc) + (size_t)srow * K + schunk;               \
      ushort* ld_ = Dmy + wid * 512;                                        \
      gload16(gs_, ld_);                                                    \
      gload16(gs_, ld_);                                                    \
    }                                                                       \
  }

#define LDA(as_, q)                                                         \
  _Pragma("unroll") for (int ii = 0; ii < 2; ++ii)                          \
  _Pragma("unroll") for (int kk = 0; kk < 2; ++kk) {                        \
    int r = wm * 128 + ((q) * 2 + ii) * 16 + fr;                            \
    af[ii][kk] = *(const bf16x8_t*)&(as_)[r * 64 + (((kk * 4 + g) ^ (r & 7)) * 8)]; \
  }

#define LDB(bs_)                                                            \
  _Pragma("unroll") for (int ni = 0; ni < 4; ++ni)                          \
  _Pragma("unroll") for (int kk = 0; kk < 2; ++kk) {                        \
    int r = wn * 64 + ni * 16 + fr;                                         \
    bfr[ni][kk] = *(const bf16x8_t*)&(bs_)[r * 64 + (((kk * 4 + g) ^ (r & 7)) * 8)]; \
  }

#define MMA(q)                                                              \
  _Pragma("unroll") for (int kk = 0; kk < 2; ++kk)                          \
  _Pragma("unroll") for (int ii = 0; ii < 2; ++ii)                          \
  _Pragma("unroll") for (int ni = 0; ni < 4; ++ni)                          \
    acc[(q) * 2 + ii][ni] = __builtin_amdgcn_mfma_f32_16x16x32_bf16(        \
        af[ii][kk], bfr[ni][kk], acc[(q) * 2 + ii][ni], 0, 0, 0);

#define BAR1                                                                \
  __builtin_amdgcn_s_barrier();                                             \
  __builtin_amdgcn_s_setprio(1);

#define BAR2                                                                \
  __builtin_amdgcn_s_setprio(0);                                            \
  __builtin_amdgcn_s_barrier();

#define BAR2VM                                                              \
  __builtin_amdgcn_s_setprio(0);                                            \
  asm volatile("s_waitcnt vmcnt(4)" ::: "memory");                          \
  __builtin_amdgcn_s_barrier();                                             \
  __builtin_amdgcn_sched_barrier(0);

  // prologue: B(0), A(0), B(1) fully staged; loop ph0/ph1 stage A(1).
  STG(Bs0, Bg, 0, 0); STG(Bs0, Bg, 0, 1);
  STG(As0, Ag, 0, 0); STG(As0, Ag, 0, 1);
  STG(Bs1, Bg, 1, 0); STG(Bs1, Bg, 1, 1);
  asm volatile("s_waitcnt vmcnt(4)" ::: "memory");
  __builtin_amdgcn_s_barrier();
  __builtin_amdgcn_sched_barrier(0);

  for (int J = 0; J < (NT >> 1); ++J) {
    const int T0 = 2 * J, T1 = 2 * J + 1;
    // ph0
    LDA(As0, 0); LDB(Bs0); STG(As1, Ag, T1, 0);
    BAR1; MMA(0); BAR2;
    // ph1
    LDA(As0, 1); STG(As1, Ag, T1, 1);
    BAR1; MMA(1); BAR2;
    // ph2
    LDA(As0, 2); STG(Bs0, Bg, T0 + 2, 0);
    BAR1; MMA(2); BAR2;
    // ph3
    LDA(As0, 3); STG(Bs0, Bg, T0 + 2, 1);
    BAR1; MMA(3); BAR2VM;
    // ph4
    LDA(As1, 0); LDB(Bs1); STG(As0, Ag, T0 + 2, 0);
    BAR1; MMA(0); BAR2;
    // ph5
    LDA(As1, 1); STG(As0, Ag, T0 + 2, 1);
    BAR1; MMA(1); BAR2;
    // ph6
    LDA(As1, 2); STG(Bs1, Bg, T1 + 2, 0);
    BAR1; MMA(2); BAR2;
    // ph7
    LDA(As1, 3); STG(Bs1, Bg, T1 + 2, 1);
    BAR1; MMA(3); BAR2VM;
  }
#undef STG
#undef LDA
#undef LDB
#undef MMA
#undef BAR1
#undef BAR2
#undef BAR2VM

  // epilogue: D col = lane&15, row = (lane>>4)*4 + reg (HW-verified mapping)
#pragma unroll
  for (int ni = 0; ni < 4; ++ni) {
    int col = n0 + wn * 64 + ni * 16 + fr;
    float bv = bias[col];
#pragma unroll
    for (int mi = 0; mi < 8; ++mi) {
      int rowbase = m0 + wm * 128 + mi * 16 + g * 4;
      if (MODE == 1) {
#pragma unroll
        for (int j = 0; j < 4; ++j)
          ((float*)Cv)[(size_t)(rowbase + j) * N + col] = acc[mi][ni][j] + bv;
      } else {
        ushort4 o;
        o.x = f2bf(acc[mi][ni][0] + bv);
        o.y = f2bf(acc[mi][ni][1] + bv);
        o.z = f2bf(acc[mi][ni][2] + bv);
        o.w = f2bf(acc[mi][ni][3] + bv);
        if (col < 2048) {
          int tt = col >> 10;           // 0=Q, 1=K
          int hh = (col >> 6) & 15;
          int d = col & 63;
          int b = rowbase >> 12;
          int s = rowbase & 4095;
          size_t off = ((((size_t)tt * BB + b) * HH + hh) * 64 + d) * SS + s;
          *(ushort4*)&qT[off] = o;     // 4 consecutive s
        } else {
          int c = col - 2048;
          vbuf[(size_t)(rowbase + 0) * HIDD + c] = o.x;
          vbuf[(size_t)(rowbase + 1) * HIDD + c] = o.y;
          vbuf[(size_t)(rowbase + 2) * HIDD + c] = o.z;
          vbuf[(size_t)(rowbase + 3) * HIDD + c] = o.w;
        }
      }
    }
  }
}

// ------- fused gram + norms + softmax: attnb[bh][64][72] bf16 -------
// 64 blocks (bh), 4 waves. Full-K (s=4096) 64x64 gram via MFMA, 3-buffer
// staging with counted vmcnt(8). Sum-of-squares accumulated from the MFMA
// fragments (af covers Q row w*16+fr; bq[w] covers K row w*16+fr).
// Then in-register scale + row softmax (shfl over fr lanes) -> bf16 attnb.
__global__ __launch_bounds__(256) void k_gram_sm(const ushort* __restrict__ qT,
                                                 const float* __restrict__ temperature,
                                                 ushort* __restrict__ attnb) {
  __shared__ ushort Qs[3][64 * 64];
  __shared__ ushort Ks[3][64 * 64];
  __shared__ ushort dmy[2048];
  __shared__ float sql[64], skl[64];
  const int bh = blockIdx.x, h = bh & 15;
  const ushort* Qp = qT + (size_t)bh * 64 * SS;
  const ushort* Kp = qT + (size_t)(BB * HH + bh) * 64 * SS;
  const int t = threadIdx.x;
  const int lane = t & 63, w = t >> 6;
  const int fr = lane & 15, g = lane >> 4;
  const int rsub = lane >> 3;
  const int gcol = ((lane & 7) ^ rsub) * 8;

  f32x4_t acc[4] = {};
  float sqa = 0.f, ska = 0.f;

#define STGG(b_, sc_)                                                       \
  _Pragma("unroll") for (int i = 0; i < 2; ++i) {                           \
    int rg = w * 2 + i;                                                     \
    int row = rg * 8 + rsub;                                                \
    gload16(&Qp[(size_t)row * SS + (sc_) * 64 + gcol], &Qs[b_][rg * 512]);  \
    gload16(&Kp[(size_t)row * SS + (sc_) * 64 + gcol], &Ks[b_][rg * 512]);  \
  }

  STGG(0, 0);
  STGG(1, 1);
  for (int sc = 0; sc < 64; ++sc) {
    if (sc + 2 < 64) {
      int b2 = (sc + 2) % 3;
      STGG(b2, sc + 2);
    } else {
#pragma unroll
      for (int i = 0; i < 2; ++i) {
        gload16(&Qp[(size_t)rsub * SS + gcol], &dmy[w * 512]);
        gload16(&Kp[(size_t)rsub * SS + gcol], &dmy[w * 512]);
      }
    }
    asm volatile("s_waitcnt vmcnt(8)" ::: "memory");
    __builtin_amdgcn_s_barrier();
    __builtin_amdgcn_sched_barrier(0);
    const int bc = sc % 3;
    bf16x8_t af[2], bq[4][2];
#pragma unroll
    for (int kk = 0; kk < 2; ++kk) {
      int r = w * 16 + fr;
      af[kk] = *(const bf16x8_t*)&Qs[bc][r * 64 + (((kk * 4 + g) ^ (r & 7)) * 8)];
    }
#pragma unroll
    for (int ni = 0; ni < 4; ++ni)
#pragma unroll
      for (int kk = 0; kk < 2; ++kk) {
        int r2 = ni * 16 + fr;
        bq[ni][kk] = *(const bf16x8_t*)&Ks[bc][r2 * 64 + (((kk * 4 + g) ^ (r2 & 7)) * 8)];
      }
#pragma unroll
    for (int kk = 0; kk < 2; ++kk)
#pragma unroll
      for (int ni = 0; ni < 4; ++ni)
        acc[ni] = __builtin_amdgcn_mfma_f32_16x16x32_bf16(af[kk], bq[ni][kk], acc[ni], 0, 0, 0);
    // sumsq from fragments: af = Q row (w*16+fr); bq[w] = K row (w*16+fr)
#pragma unroll
    for (int kk = 0; kk < 2; ++kk)
#pragma unroll
      for (int e = 0; e < 8; ++e) {
        float fq = bf2f((ushort)af[kk][e]);
        sqa += fq * fq;
        float fk = bf2f((ushort)bq[w][kk][e]);
        ska += fk * fk;
      }
    __builtin_amdgcn_s_barrier();
    __builtin_amdgcn_sched_barrier(0);
  }
#undef STGG

  // reduce per-row sumsq over the 4 g-lanes
  sqa += __shfl_xor(sqa, 16, 64); sqa += __shfl_xor(sqa, 32, 64);
  ska += __shfl_xor(ska, 16, 64); ska += __shfl_xor(ska, 32, 64);
  if (g == 0) { sql[w * 16 + fr] = sqa; skl[w * 16 + fr] = ska; }
  __syncthreads();

  float tscale = temperature[h] * (1.0f / 32.0f);
  float ik[4];
#pragma unroll
  for (int ni = 0; ni < 4; ++ni)
    ik[ni] = 1.0f / fmaxf(sqrtf(skl[ni * 16 + fr]), 1e-12f);
#pragma unroll
  for (int j = 0; j < 4; ++j) {
    int row = w * 16 + g * 4 + j;
    float iq = 1.0f / fmaxf(sqrtf(sql[row]), 1e-12f);
    float v[4];
#pragma unroll
    for (int ni = 0; ni < 4; ++ni) v[ni] = acc[ni][j] * iq * ik[ni] * tscale;
    float m = fmaxf(fmaxf(v[0], v[1]), fmaxf(v[2], v[3]));
#pragma unroll
    for (int off = 1; off < 16; off <<= 1) m = fmaxf(m, __shfl_xor(m, off, 64));
    float p[4], s = 0.f;
#pragma unroll
    for (int ni = 0; ni < 4; ++ni) { p[ni] = __expf(v[ni] - m); s += p[ni]; }
#pragma unroll
    for (int off = 1; off < 16; off <<= 1) s += __shfl_xor(s, off, 64);
    float inv = 1.0f / s;
#pragma unroll
    for (int ni = 0; ni < 4; ++ni)
      attnb[(size_t)bh * 4608 + row * 72 + ni * 16 + fr] = f2bf(p[ni] * inv);
  }
}

// ---------------- PV (MFMA): out[s][d] = sum_e V[s,e] * attn[d,e] ----------------
__global__ __launch_bounds__(256) void k_pv(const ushort* __restrict__ vbuf,
                                            const ushort* __restrict__ attnb,
                                            ushort* __restrict__ attnout) {
  __shared__ ushort Vs[64 * 64];
  int bh = blockIdx.x, p = blockIdx.y;
  int b = bh >> 4, h = bh & 15;
  const int t = threadIdx.x;
  const int lane = t & 63, w = t >> 6;
  const int fr = lane & 15, g = lane >> 4;
  const int rsub = lane >> 3;
  const int gcol = ((lane & 7) ^ rsub) * 8;

  // B-frags straight from global attnb (L2-hot, 16B aligned: 144B row stride)
  bf16x8_t bfg[4][2];
#pragma unroll
  for (int ni = 0; ni < 4; ++ni)
#pragma unroll
    for (int kk = 0; kk < 2; ++kk)
      bfg[ni][kk] = *(const bf16x8_t*)&attnb[(size_t)bh * 4608 + (ni * 16 + fr) * 72 + (kk * 4 + g) * 8];

  const ushort* vb = vbuf + (size_t)(b * SS + p * 1024) * HIDD + h * 64;
  ushort* ob = attnout + (size_t)(b * SS + p * 1024) * HIDD + h * 64;
  for (int s0 = 0; s0 < 1024; s0 += 64) {
#pragma unroll
    for (int i = 0; i < 2; ++i) {
      int rg = w * 2 + i;
      int row = rg * 8 + rsub;
      gload16(&vb[(size_t)(s0 + row) * HIDD + gcol], &Vs[rg * 512]);
    }
    __syncthreads();
    f32x4_t acc[4] = {};
#pragma unroll
    for (int kk = 0; kk < 2; ++kk) {
      int r = w * 16 + fr;  // s-row within chunk
      bf16x8_t af = *(const bf16x8_t*)&Vs[r * 64 + (((kk * 4 + g) ^ (r & 7)) * 8)];
#pragma unroll
      for (int ni = 0; ni < 4; ++ni)
        acc[ni] = __builtin_amdgcn_mfma_f32_16x16x32_bf16(af, bfg[ni][kk], acc[ni], 0, 0, 0);
    }
#pragma unroll
    for (int ni = 0; ni < 4; ++ni)
#pragma unroll
      for (int j = 0; j < 4; ++j)
        ob[(size_t)(s0 + w * 16 + g * 4 + j) * HIDD + ni * 16 + fr] = f2bf(acc[ni][j]);
    __syncthreads();
  }
}

extern "C" void kernel_launch(void* const* d_in, const int* in_sizes, int n_in,
                              void* d_out, int out_size, void* d_ws, size_t ws_size,
                              hipStream_t stream) {
  const float* x = (const float*)d_in[0];
  const float* Wqkv = (const float*)d_in[1];
  const float* bqkv = (const float*)d_in[2];
  const float* Wz = (const float*)d_in[3];
  const float* bz = (const float*)d_in[4];
  const float* temperature = (const float*)d_in[5];

  char* ws = (char*)d_ws;
  ushort* xb    = (ushort*)(ws + 0);           // 33,554,432 (alias: attnout)
  ushort* wqb   = (ushort*)(ws + 33554432);    // 6,291,456
  ushort* wzb   = (ushort*)(ws + 39845888);    // 2,097,152
  ushort* vbuf  = (ushort*)(ws + 41943040);    // 33,554,432
  ushort* qkvT  = (ushort*)(ws + 75497472);    // 67,108,864  [t][b][h][d][s]
  ushort* attnb = (ushort*)(ws + 142639104);   // 589,824  [bh][64][72]
  ushort* attnout = xb;  // x is dead after QKV GEMM

  // 1) converts
  k_f2bf<<<dim3(16384), dim3(256), 0, stream>>>(x, xb, (MM * HIDD) / 4);
  k_f2bf<<<dim3(3072), dim3(256), 0, stream>>>(Wqkv, wqb, (NQKV * HIDD) / 4);
  k_f2bf<<<dim3(1024), dim3(256), 0, stream>>>(Wz, wzb, (HIDD * HIDD) / 4);

  // 2) QKV GEMM -> QT/KT transposed + V natural
  k_gemm8p<2><<<dim3(MM / 256, NQKV / 256), dim3(512), 0, stream>>>(
      xb, wqb, bqkv, nullptr, qkvT, vbuf, MM, NQKV, HIDD);

  // 3) fused gram + norms + softmax
  k_gram_sm<<<dim3(64), dim3(256), 0, stream>>>(qkvT, temperature, attnb);

  // 4) PV (MFMA)
  k_pv<<<dim3(64, 4), dim3(256), 0, stream>>>(vbuf, attnb, attnout);

  // 5) output GEMM -> d_out fp32
  k_gemm8p<1><<<dim3(MM / 256, HIDD / 256), dim3(512), 0, stream>>>(
      attnout, wzb, bz, d_out, nullptr, nullptr, MM, HIDD, HIDD);
}

// Round 7
// 354.719 us; speedup vs baseline: 1.9101x; 1.9101x over previous
//
#include <hip/hip_runtime.h>

#define DEVINL __device__ __forceinline__

// Problem constants
#define BB 4
#define SS 4096
#define HIDD 1024
#define HH 16
#define DH 64
#define NQKV 3072
#define MM (BB * SS)  // 16384

typedef __attribute__((ext_vector_type(8))) short bf16x8_t;
typedef __attribute__((ext_vector_type(4))) float f32x4_t;

typedef __attribute__((address_space(1))) const void GV;
typedef __attribute__((address_space(3))) void LV;

DEVINL void gload16(const void* g, void* l) {
  // async global->LDS, 16B/lane; LDS dest = wave-uniform base + lane*16
  __builtin_amdgcn_global_load_lds((GV*)g, (LV*)l, 16, 0, 0);
}

DEVINL float bf2f(ushort u) {
  union { unsigned int i; float f; } v;
  v.i = ((unsigned int)u) << 16;
  return v.f;
}
DEVINL ushort f2bf(float f) {
  unsigned int u = __float_as_uint(f);
  u = (u + 0x7fffu + ((u >> 16) & 1u)) >> 16;
  return (ushort)u;
}

// ---------------- fp32 -> bf16 convert (4 elems/thread) ----------------
__global__ __launch_bounds__(256) void k_f2bf(const float* __restrict__ src,
                                              ushort* __restrict__ dst, int n4) {
  int i = blockIdx.x * 256 + threadIdx.x;
  if (i >= n4) return;
  float4 v = ((const float4*)src)[i];
  ushort4 o;
  o.x = f2bf(v.x); o.y = f2bf(v.y); o.z = f2bf(v.z); o.w = f2bf(v.w);
  ((ushort4*)dst)[i] = o;
}

// ---------------- 8-phase 256x256 bf16 GEMM, compile-time geometry ----------
// 8 waves (2M x 4N), BK=64, acc 8x4 frags of 16x16x32. 2 LDS K-tile slots per
// operand + dummy; per phase {ds_read quad (+B at q0) | stage 1 half-tile},
// barrier/setprio around MFMA, counted vmcnt(4) at ph3/ph7 only. J fully
// unrolled (KDIM constexpr) so all addresses are base+constant.
template <int MODE, int MDIM, int NDIM, int KDIM>
__global__ __launch_bounds__(512, 2) void k_gemm8p(
    const ushort* __restrict__ A, const ushort* __restrict__ B,
    const float* __restrict__ bias, void* __restrict__ Cv,
    ushort* __restrict__ qT, ushort* __restrict__ vbuf) {
  __shared__ ushort As0[256 * 64];
  __shared__ ushort As1[256 * 64];
  __shared__ ushort Bs0[256 * 64];
  __shared__ ushort Bs1[256 * 64];
  __shared__ ushort Dmy[4096];
  constexpr int NT = KDIM >> 6;
  const int t = threadIdx.x;
  const int m0 = blockIdx.x * 256, n0 = blockIdx.y * 256;
  const int lane = t & 63, wid = t >> 6;
  const int wm = wid >> 2, wn = wid & 3;   // 2M x 4N waves
  const int fr = lane & 15, g = lane >> 4;
  const int srow = t >> 3;                        // 0..63 (row within 64-row call)
  const int schunk = ((t & 7) ^ (srow & 7)) * 8;  // pre-swizzled 16B chunk
  // per-thread staging bases (all further addressing is +constexpr)
  const ushort* Ab = A + (size_t)(m0 + srow) * KDIM + schunk;
  const ushort* Bb = B + (size_t)(n0 + srow) * KDIM + schunk;

  f32x4_t acc[8][4] = {};
  bf16x8_t af[2][2], bfr[4][2];

#define STG(ls_, gb_, tile, hf)                                             \
  {                                                                         \
    if ((tile) < NT) {                                                      \
      gload16((gb_) + (size_t)((hf) * 128) * KDIM + (tile) * 64,            \
              (ls_) + ((hf) * 128 + wid * 8) * 64);                         \
      gload16((gb_) + (size_t)((hf) * 128 + 64) * KDIM + (tile) * 64,       \
              (ls_) + ((hf) * 128 + wid * 8 + 64) * 64);                    \
    } else {                                                                \
      gload16((gb_), Dmy + wid * 512);                                      \
      gload16((gb_), Dmy + wid * 512);                                      \
    }                                                                       \
  }

#define LDA(as_, q)                                                         \
  _Pragma("unroll") for (int ii = 0; ii < 2; ++ii)                          \
  _Pragma("unroll") for (int kk = 0; kk < 2; ++kk) {                        \
    int r = wm * 128 + ((q) * 2 + ii) * 16 + fr;                            \
    af[ii][kk] = *(const bf16x8_t*)&(as_)[r * 64 + (((kk * 4 + g) ^ (r & 7)) * 8)]; \
  }

#define LDB(bs_)                                                            \
  _Pragma("unroll") for (int ni = 0; ni < 4; ++ni)                          \
  _Pragma("unroll") for (int kk = 0; kk < 2; ++kk) {                        \
    int r = wn * 64 + ni * 16 + fr;                                         \
    bfr[ni][kk] = *(const bf16x8_t*)&(bs_)[r * 64 + (((kk * 4 + g) ^ (r & 7)) * 8)]; \
  }

#define MMA(q)                                                              \
  _Pragma("unroll") for (int kk = 0; kk < 2; ++kk)                          \
  _Pragma("unroll") for (int ii = 0; ii < 2; ++ii)                          \
  _Pragma("unroll") for (int ni = 0; ni < 4; ++ni)                          \
    acc[(q) * 2 + ii][ni] = __builtin_amdgcn_mfma_f32_16x16x32_bf16(        \
        af[ii][kk], bfr[ni][kk], acc[(q) * 2 + ii][ni], 0, 0, 0);

#define BAR1                                                                \
  __builtin_amdgcn_s_barrier();                                             \
  __builtin_amdgcn_s_setprio(1);

#define BAR2                                                                \
  __builtin_amdgcn_s_setprio(0);                                            \
  __builtin_amdgcn_s_barrier();

#define BAR2VM                                                              \
  __builtin_amdgcn_s_setprio(0);                                            \
  asm volatile("s_waitcnt vmcnt(4)" ::: "memory");                          \
  __builtin_amdgcn_s_barrier();                                             \
  __builtin_amdgcn_sched_barrier(0);

  // prologue: B(0), A(0), B(1) fully staged; loop ph0/ph1 stage A(1).
  STG(Bs0, Bb, 0, 0); STG(Bs0, Bb, 0, 1);
  STG(As0, Ab, 0, 0); STG(As0, Ab, 0, 1);
  STG(Bs1, Bb, 1, 0); STG(Bs1, Bb, 1, 1);
  asm volatile("s_waitcnt vmcnt(4)" ::: "memory");
  __builtin_amdgcn_s_barrier();
  __builtin_amdgcn_sched_barrier(0);

#pragma unroll
  for (int J = 0; J < (NT >> 1); ++J) {
    const int T0 = 2 * J, T1 = 2 * J + 1;
    LDA(As0, 0); LDB(Bs0); STG(As1, Ab, T1, 0);
    BAR1; MMA(0); BAR2;
    LDA(As0, 1); STG(As1, Ab, T1, 1);
    BAR1; MMA(1); BAR2;
    LDA(As0, 2); STG(Bs0, Bb, T0 + 2, 0);
    BAR1; MMA(2); BAR2;
    LDA(As0, 3); STG(Bs0, Bb, T0 + 2, 1);
    BAR1; MMA(3); BAR2VM;
    LDA(As1, 0); LDB(Bs1); STG(As0, Ab, T0 + 2, 0);
    BAR1; MMA(0); BAR2;
    LDA(As1, 1); STG(As0, Ab, T0 + 2, 1);
    BAR1; MMA(1); BAR2;
    LDA(As1, 2); STG(Bs1, Bb, T1 + 2, 0);
    BAR1; MMA(2); BAR2;
    LDA(As1, 3); STG(Bs1, Bb, T1 + 2, 1);
    BAR1; MMA(3); BAR2VM;
  }
#undef STG
#undef LDA
#undef LDB
#undef MMA
#undef BAR1
#undef BAR2
#undef BAR2VM

  // epilogue: D col = lane&15, row = (lane>>4)*4 + reg (HW-verified mapping)
#pragma unroll
  for (int ni = 0; ni < 4; ++ni) {
    int col = n0 + wn * 64 + ni * 16 + fr;
    float bv = bias[col];
#pragma unroll
    for (int mi = 0; mi < 8; ++mi) {
      int rowbase = m0 + wm * 128 + mi * 16 + g * 4;
      if (MODE == 1) {
#pragma unroll
        for (int j = 0; j < 4; ++j)
          ((float*)Cv)[(size_t)(rowbase + j) * NDIM + col] = acc[mi][ni][j] + bv;
      } else {
        ushort4 o;
        o.x = f2bf(acc[mi][ni][0] + bv);
        o.y = f2bf(acc[mi][ni][1] + bv);
        o.z = f2bf(acc[mi][ni][2] + bv);
        o.w = f2bf(acc[mi][ni][3] + bv);
        if (col < 2048) {
          int tt = col >> 10;           // 0=Q, 1=K
          int hh = (col >> 6) & 15;
          int d = col & 63;
          int b = rowbase >> 12;
          int s = rowbase & 4095;
          size_t off = ((((size_t)tt * BB + b) * HH + hh) * 64 + d) * SS + s;
          *(ushort4*)&qT[off] = o;     // 4 consecutive s
        } else {
          int c = col - 2048;
          vbuf[(size_t)(rowbase + 0) * HIDD + c] = o.x;
          vbuf[(size_t)(rowbase + 1) * HIDD + c] = o.y;
          vbuf[(size_t)(rowbase + 2) * HIDD + c] = o.z;
          vbuf[(size_t)(rowbase + 3) * HIDD + c] = o.w;
        }
      }
    }
  }
}

// ------- gram quarter + fused sumsq partials (verified round-6 math) -------
// grid (64 bh, 4 p). 3-buffer counted-vmcnt staging; per chunk 8 MFMA/wave.
// Partials to d_out scratch: Wp4[bh*4+p][64][64] f32, sq4/sk4[bh*4+p][64].
__global__ __launch_bounds__(256) void k_gram(const ushort* __restrict__ qT,
                                              float* __restrict__ Wp4,
                                              float* __restrict__ sq4,
                                              float* __restrict__ sk4) {
  __shared__ ushort Qs[3][64 * 64];
  __shared__ ushort Ks[3][64 * 64];
  __shared__ float sql[64], skl[64];
  const int bh = blockIdx.x, p = blockIdx.y;
  const ushort* Qp = qT + (size_t)bh * 64 * SS + p * 1024;
  const ushort* Kp = qT + (size_t)(BB * HH + bh) * 64 * SS + p * 1024;
  const int t = threadIdx.x;
  const int lane = t & 63, w = t >> 6;
  const int fr = lane & 15, g = lane >> 4;
  const int rsub = lane >> 3;
  const int gcol = ((lane & 7) ^ rsub) * 8;

  f32x4_t acc[4] = {};
  float sqa = 0.f, ska = 0.f;

#define STGG(b_, sc_)                                                       \
  _Pragma("unroll") for (int i = 0; i < 2; ++i) {                           \
    int rg = w * 2 + i;                                                     \
    int row = rg * 8 + rsub;                                                \
    gload16(&Qp[(size_t)row * SS + (sc_) * 64 + gcol], &Qs[b_][rg * 512]);  \
    gload16(&Kp[(size_t)row * SS + (sc_) * 64 + gcol], &Ks[b_][rg * 512]);  \
  }

#define GCOMP(bc)                                                           \
  {                                                                         \
    bf16x8_t af[2], bq[4][2];                                               \
    _Pragma("unroll") for (int kk = 0; kk < 2; ++kk) {                      \
      int r = w * 16 + fr;                                                  \
      af[kk] = *(const bf16x8_t*)&Qs[bc][r * 64 + (((kk * 4 + g) ^ (r & 7)) * 8)]; \
    }                                                                       \
    _Pragma("unroll") for (int ni = 0; ni < 4; ++ni)                        \
    _Pragma("unroll") for (int kk = 0; kk < 2; ++kk) {                      \
      int r2 = ni * 16 + fr;                                                \
      bq[ni][kk] = *(const bf16x8_t*)&Ks[bc][r2 * 64 + (((kk * 4 + g) ^ (r2 & 7)) * 8)]; \
    }                                                                       \
    _Pragma("unroll") for (int kk = 0; kk < 2; ++kk)                        \
    _Pragma("unroll") for (int ni = 0; ni < 4; ++ni)                        \
      acc[ni] = __builtin_amdgcn_mfma_f32_16x16x32_bf16(af[kk], bq[ni][kk], acc[ni], 0, 0, 0); \
    _Pragma("unroll") for (int kk = 0; kk < 2; ++kk)                        \
    _Pragma("unroll") for (int e = 0; e < 8; ++e) {                         \
      float fq = bf2f((ushort)af[kk][e]);                                   \
      sqa += fq * fq;                                                       \
      float fk = bf2f((ushort)bq[w][kk][e]);                                \
      ska += fk * fk;                                                       \
    }                                                                       \
  }

#define GWAIT(n_)                                                           \
  asm volatile("s_waitcnt vmcnt(" #n_ ")" ::: "memory");                    \
  __builtin_amdgcn_s_barrier();                                             \
  __builtin_amdgcn_sched_barrier(0);

  STGG(0, 0);
  STGG(1, 1);
  for (int sc = 0; sc < 14; ++sc) {
    STGG((sc + 2) % 3, sc + 2);
    GWAIT(8);
    GCOMP(sc % 3);
    __builtin_amdgcn_s_barrier();
  }
  GWAIT(4); GCOMP(14 % 3); __builtin_amdgcn_s_barrier();
  GWAIT(0); GCOMP(15 % 3);
#undef STGG
#undef GCOMP
#undef GWAIT

  // reduce per-row sumsq over the 4 g-lanes; write partials
  sqa += __shfl_xor(sqa, 16, 64); sqa += __shfl_xor(sqa, 32, 64);
  ska += __shfl_xor(ska, 16, 64); ska += __shfl_xor(ska, 32, 64);
  const int bp = bh * 4 + p;
  if (g == 0) {
    sq4[bp * 64 + w * 16 + fr] = sqa;
    sk4[bp * 64 + w * 16 + fr] = ska;
  }
  float* wp = Wp4 + (size_t)bp * 4096;
#pragma unroll
  for (int ni = 0; ni < 4; ++ni)
#pragma unroll
    for (int j = 0; j < 4; ++j)
      wp[(w * 16 + g * 4 + j) * 64 + ni * 16 + fr] = acc[ni][j];
}

// ------- smx: combine partials, scale, softmax -> bf16 attnb[bh][64][72] ----
__global__ __launch_bounds__(256) void k_smx(const float* __restrict__ Wp4,
                                             const float* __restrict__ sq4,
                                             const float* __restrict__ sk4,
                                             const float* __restrict__ temperature,
                                             ushort* __restrict__ attnb) {
  __shared__ float attnf[64][65];
  __shared__ float iqL[64], ikL[64], invs[64];
  const int bh = blockIdx.x, h = bh & 15;
  const int t = threadIdx.x;
  if (t < 64) {
    float sq = 0.f, sk = 0.f;
#pragma unroll
    for (int p = 0; p < 4; ++p) {
      sq += sq4[(bh * 4 + p) * 64 + t];
      sk += sk4[(bh * 4 + p) * 64 + t];
    }
    iqL[t] = 1.0f / fmaxf(sqrtf(sq), 1e-12f);
    ikL[t] = 1.0f / fmaxf(sqrtf(sk), 1e-12f);
  }
  __syncthreads();
  float tscale = temperature[h] * (1.0f / 32.0f);
  for (int idx = t; idx < 4096; idx += 256) {
    int d = idx >> 6, e = idx & 63;
    float s = 0.f;
#pragma unroll
    for (int p = 0; p < 4; ++p) s += Wp4[(size_t)(bh * 4 + p) * 4096 + idx];
    attnf[d][e] = s * iqL[d] * ikL[e] * tscale;
  }
  __syncthreads();
  if (t < 64) {
    float m = -1e30f;
#pragma unroll 8
    for (int e = 0; e < 64; ++e) m = fmaxf(m, attnf[t][e]);
    float sum = 0.f;
#pragma unroll 8
    for (int e = 0; e < 64; ++e) {
      float v = __expf(attnf[t][e] - m);
      attnf[t][e] = v;
      sum += v;
    }
    invs[t] = 1.0f / sum;
  }
  __syncthreads();
  for (int idx = t; idx < 4096; idx += 256) {
    int d = idx >> 6, e = idx & 63;
    attnb[(size_t)bh * 4608 + d * 72 + e] = f2bf(attnf[d][e] * invs[d]);
  }
}

// ---------------- PV (MFMA): out[s][d] = sum_e V[s,e] * attn[d,e] ----------
// grid (64 bh, 8 p): 512 s-rows per block, 3-buffer counted-vmcnt staging.
__global__ __launch_bounds__(256) void k_pv(const ushort* __restrict__ vbuf,
                                            const ushort* __restrict__ attnb,
                                            ushort* __restrict__ attnout) {
  __shared__ ushort Vs[3][64 * 64];
  const int bh = blockIdx.x, p = blockIdx.y;
  const int b = bh >> 4, h = bh & 15;
  const int t = threadIdx.x;
  const int lane = t & 63, w = t >> 6;
  const int fr = lane & 15, g = lane >> 4;
  const int rsub = lane >> 3;
  const int gcol = ((lane & 7) ^ rsub) * 8;

  // B-frags straight from global attnb (L2-hot)
  bf16x8_t bfg[4][2];
#pragma unroll
  for (int ni = 0; ni < 4; ++ni)
#pragma unroll
    for (int kk = 0; kk < 2; ++kk)
      bfg[ni][kk] = *(const bf16x8_t*)&attnb[(size_t)bh * 4608 + (ni * 16 + fr) * 72 + (kk * 4 + g) * 8];

  const ushort* vb = vbuf + (size_t)(b * SS + p * 512) * HIDD + h * 64;
  ushort* ob = attnout + (size_t)(b * SS + p * 512) * HIDD + h * 64;

#define STGV(b_, c_)                                                        \
  _Pragma("unroll") for (int i = 0; i < 2; ++i) {                           \
    int rg = w * 2 + i;                                                     \
    int row = rg * 8 + rsub;                                                \
    gload16(&vb[(size_t)((c_) * 64 + row) * HIDD + gcol], &Vs[b_][rg * 512]); \
  }

#define PCOMP(bc, c_)                                                       \
  {                                                                         \
    f32x4_t acc[4] = {};                                                    \
    _Pragma("unroll") for (int kk = 0; kk < 2; ++kk) {                      \
      int r = w * 16 + fr;                                                  \
      bf16x8_t af = *(const bf16x8_t*)&Vs[bc][r * 64 + (((kk * 4 + g) ^ (r & 7)) * 8)]; \
      _Pragma("unroll") for (int ni = 0; ni < 4; ++ni)                      \
        acc[ni] = __builtin_amdgcn_mfma_f32_16x16x32_bf16(af, bfg[ni][kk], acc[ni], 0, 0, 0); \
    }                                                                       \
    _Pragma("unroll") for (int ni = 0; ni < 4; ++ni)                        \
    _Pragma("unroll") for (int j = 0; j < 4; ++j)                           \
      ob[(size_t)((c_) * 64 + w * 16 + g * 4 + j) * HIDD + ni * 16 + fr] = f2bf(acc[ni][j]); \
  }

#define PWAIT(n_)                                                           \
  asm volatile("s_waitcnt vmcnt(" #n_ ")" ::: "memory");                    \
  __builtin_amdgcn_s_barrier();                                             \
  __builtin_amdgcn_sched_barrier(0);

  STGV(0, 0);
  STGV(1, 1);
  for (int c = 0; c < 6; ++c) {
    STGV((c + 2) % 3, c + 2);
    PWAIT(4);
    PCOMP(c % 3, c);
    __builtin_amdgcn_s_barrier();
  }
  PWAIT(2); PCOMP(0, 6); __builtin_amdgcn_s_barrier();
  PWAIT(0); PCOMP(1, 7);
#undef STGV
#undef PCOMP
#undef PWAIT
}

extern "C" void kernel_launch(void* const* d_in, const int* in_sizes, int n_in,
                              void* d_out, int out_size, void* d_ws, size_t ws_size,
                              hipStream_t stream) {
  const float* x = (const float*)d_in[0];
  const float* Wqkv = (const float*)d_in[1];
  const float* bqkv = (const float*)d_in[2];
  const float* Wz = (const float*)d_in[3];
  const float* bz = (const float*)d_in[4];
  const float* temperature = (const float*)d_in[5];

  char* ws = (char*)d_ws;
  ushort* xb    = (ushort*)(ws + 0);           // 33,554,432 (alias: attnout)
  ushort* wqb   = (ushort*)(ws + 33554432);    // 6,291,456
  ushort* wzb   = (ushort*)(ws + 39845888);    // 2,097,152
  ushort* vbuf  = (ushort*)(ws + 41943040);    // 33,554,432
  ushort* qkvT  = (ushort*)(ws + 75497472);    // 67,108,864  [t][b][h][d][s]
  ushort* attnout = xb;  // x is dead after QKV GEMM

  // scratch inside d_out (64 MB, fully overwritten by GEMM2 at the end):
  float* dsc = (float*)d_out;
  float* Wp4 = dsc;                        // 1,048,576 floats (4 MB)
  float* sq4 = dsc + 1048576;              // 16,384 floats
  float* sk4 = dsc + 1048576 + 16384;      // 16,384 floats
  ushort* attnb = (ushort*)(dsc + 1048576 + 32768);  // 294,912 ushorts

  // 1) converts
  k_f2bf<<<dim3(16384), dim3(256), 0, stream>>>(x, xb, (MM * HIDD) / 4);
  k_f2bf<<<dim3(3072), dim3(256), 0, stream>>>(Wqkv, wqb, (NQKV * HIDD) / 4);
  k_f2bf<<<dim3(1024), dim3(256), 0, stream>>>(Wz, wzb, (HIDD * HIDD) / 4);

  // 2) QKV GEMM -> QT/KT transposed + V natural
  k_gemm8p<2, MM, NQKV, HIDD><<<dim3(MM / 256, NQKV / 256), dim3(512), 0, stream>>>(
      xb, wqb, bqkv, nullptr, qkvT, vbuf);

  // 3) gram quarters (+fused sumsq) -> combine+softmax
  k_gram<<<dim3(64, 4), dim3(256), 0, stream>>>(qkvT, Wp4, sq4, sk4);
  k_smx<<<dim3(64), dim3(256), 0, stream>>>(Wp4, sq4, sk4, temperature, attnb);

  // 4) PV (MFMA)
  k_pv<<<dim3(64, 8), dim3(256), 0, stream>>>(vbuf, attnb, attnout);

  // 5) output GEMM -> d_out fp32 (overwrites the scratch)
  k_gemm8p<1, MM, HIDD, HIDD><<<dim3(MM / 256, HIDD / 256), dim3(512), 0, stream>>>(
      attnout, wzb, bz, d_out, nullptr, nullptr);
}

// Round 8
// 224.555 us; speedup vs baseline: 3.0174x; 1.5797x over previous
//
#include <hip/hip_runtime.h>

#define DEVINL __device__ __forceinline__

// Problem constants
#define BB 4
#define SS 4096
#define HIDD 1024
#define HH 16
#define DH 64
#define NQKV 3072
#define MM (BB * SS)  // 16384

typedef __attribute__((ext_vector_type(8))) short bf16x8_t;
typedef __attribute__((ext_vector_type(4))) float f32x4_t;

typedef __attribute__((address_space(1))) const void GV;
typedef __attribute__((address_space(3))) void LV;

DEVINL void gload16(const void* g, void* l) {
  // async global->LDS, 16B/lane; LDS dest = wave-uniform base + lane*16
  __builtin_amdgcn_global_load_lds((GV*)g, (LV*)l, 16, 0, 0);
}

DEVINL float bf2f(ushort u) {
  union { unsigned int i; float f; } v;
  v.i = ((unsigned int)u) << 16;
  return v.f;
}
DEVINL ushort f2bf(float f) {
  unsigned int u = __float_as_uint(f);
  u = (u + 0x7fffu + ((u >> 16) & 1u)) >> 16;
  return (ushort)u;
}

// ---------------- fp32 -> bf16 convert (4 elems/thread) ----------------
__global__ __launch_bounds__(256) void k_f2bf(const float* __restrict__ src,
                                              ushort* __restrict__ dst, int n4) {
  int i = blockIdx.x * 256 + threadIdx.x;
  if (i >= n4) return;
  float4 v = ((const float4*)src)[i];
  ushort4 o;
  o.x = f2bf(v.x); o.y = f2bf(v.y); o.z = f2bf(v.z); o.w = f2bf(v.w);
  ((ushort4*)dst)[i] = o;
}

// ---------------- 8-phase 256x256 bf16 GEMM, compile-time geometry ----------
// 8 waves (2M x 4N), BK=64, acc 8x4 frags of 16x16x32. 2 LDS K-tile slots per
// operand + dummy; per phase {ds_read quad (+B at q0) | stage 1 half-tile},
// barrier/setprio around MFMA, counted vmcnt(4) at ph3/ph7 only. J fully
// unrolled (KDIM constexpr) so all addresses are base+constant.
template <int MODE, int MDIM, int NDIM, int KDIM>
__global__ __launch_bounds__(512, 2) void k_gemm8p(
    const ushort* __restrict__ A, const ushort* __restrict__ B,
    const float* __restrict__ bias, void* __restrict__ Cv,
    ushort* __restrict__ qT, ushort* __restrict__ vbuf) {
  __shared__ ushort As0[256 * 64];
  __shared__ ushort As1[256 * 64];
  __shared__ ushort Bs0[256 * 64];
  __shared__ ushort Bs1[256 * 64];
  __shared__ ushort Dmy[4096];
  constexpr int NT = KDIM >> 6;
  const int t = threadIdx.x;
  const int m0 = blockIdx.x * 256, n0 = blockIdx.y * 256;
  const int lane = t & 63, wid = t >> 6;
  const int wm = wid >> 2, wn = wid & 3;   // 2M x 4N waves
  const int fr = lane & 15, g = lane >> 4;
  const int srow = t >> 3;                        // 0..63 (row within 64-row call)
  const int schunk = ((t & 7) ^ (srow & 7)) * 8;  // pre-swizzled 16B chunk
  // per-thread staging bases (all further addressing is +constexpr)
  const ushort* Ab = A + (size_t)(m0 + srow) * KDIM + schunk;
  const ushort* Bb = B + (size_t)(n0 + srow) * KDIM + schunk;

  f32x4_t acc[8][4] = {};
  bf16x8_t af[2][2], bfr[4][2];

#define STG(ls_, gb_, tile, hf)                                             \
  {                                                                         \
    if ((tile) < NT) {                                                      \
      gload16((gb_) + (size_t)((hf) * 128) * KDIM + (tile) * 64,            \
              (ls_) + ((hf) * 128 + wid * 8) * 64);                         \
      gload16((gb_) + (size_t)((hf) * 128 + 64) * KDIM + (tile) * 64,       \
              (ls_) + ((hf) * 128 + wid * 8 + 64) * 64);                    \
    } else {                                                                \
      gload16((gb_), Dmy + wid * 512);                                      \
      gload16((gb_), Dmy + wid * 512);                                      \
    }                                                                       \
  }

#define LDA(as_, q)                                                         \
  _Pragma("unroll") for (int ii = 0; ii < 2; ++ii)                          \
  _Pragma("unroll") for (int kk = 0; kk < 2; ++kk) {                        \
    int r = wm * 128 + ((q) * 2 + ii) * 16 + fr;                            \
    af[ii][kk] = *(const bf16x8_t*)&(as_)[r * 64 + (((kk * 4 + g) ^ (r & 7)) * 8)]; \
  }

#define LDB(bs_)                                                            \
  _Pragma("unroll") for (int ni = 0; ni < 4; ++ni)                          \
  _Pragma("unroll") for (int kk = 0; kk < 2; ++kk) {                        \
    int r = wn * 64 + ni * 16 + fr;                                         \
    bfr[ni][kk] = *(const bf16x8_t*)&(bs_)[r * 64 + (((kk * 4 + g) ^ (r & 7)) * 8)]; \
  }

#define MMA(q)                                                              \
  _Pragma("unroll") for (int kk = 0; kk < 2; ++kk)                          \
  _Pragma("unroll") for (int ii = 0; ii < 2; ++ii)                          \
  _Pragma("unroll") for (int ni = 0; ni < 4; ++ni)                          \
    acc[(q) * 2 + ii][ni] = __builtin_amdgcn_mfma_f32_16x16x32_bf16(        \
        af[ii][kk], bfr[ni][kk], acc[(q) * 2 + ii][ni], 0, 0, 0);

#define BAR1                                                                \
  __builtin_amdgcn_s_barrier();                                             \
  __builtin_amdgcn_s_setprio(1);

#define BAR2                                                                \
  __builtin_amdgcn_s_setprio(0);                                            \
  __builtin_amdgcn_s_barrier();

#define BAR2VM                                                              \
  __builtin_amdgcn_s_setprio(0);                                            \
  asm volatile("s_waitcnt vmcnt(4)" ::: "memory");                          \
  __builtin_amdgcn_s_barrier();                                             \
  __builtin_amdgcn_sched_barrier(0);

  // prologue: B(0), A(0), B(1) fully staged; loop ph0/ph1 stage A(1).
  STG(Bs0, Bb, 0, 0); STG(Bs0, Bb, 0, 1);
  STG(As0, Ab, 0, 0); STG(As0, Ab, 0, 1);
  STG(Bs1, Bb, 1, 0); STG(Bs1, Bb, 1, 1);
  asm volatile("s_waitcnt vmcnt(4)" ::: "memory");
  __builtin_amdgcn_s_barrier();
  __builtin_amdgcn_sched_barrier(0);

#pragma unroll
  for (int J = 0; J < (NT >> 1); ++J) {
    const int T0 = 2 * J, T1 = 2 * J + 1;
    LDA(As0, 0); LDB(Bs0); STG(As1, Ab, T1, 0);
    BAR1; MMA(0); BAR2;
    LDA(As0, 1); STG(As1, Ab, T1, 1);
    BAR1; MMA(1); BAR2;
    LDA(As0, 2); STG(Bs0, Bb, T0 + 2, 0);
    BAR1; MMA(2); BAR2;
    LDA(As0, 3); STG(Bs0, Bb, T0 + 2, 1);
    BAR1; MMA(3); BAR2VM;
    LDA(As1, 0); LDB(Bs1); STG(As0, Ab, T0 + 2, 0);
    BAR1; MMA(0); BAR2;
    LDA(As1, 1); STG(As0, Ab, T0 + 2, 1);
    BAR1; MMA(1); BAR2;
    LDA(As1, 2); STG(Bs1, Bb, T1 + 2, 0);
    BAR1; MMA(2); BAR2;
    LDA(As1, 3); STG(Bs1, Bb, T1 + 2, 1);
    BAR1; MMA(3); BAR2VM;
  }
#undef STG
#undef LDA
#undef LDB
#undef MMA
#undef BAR1
#undef BAR2
#undef BAR2VM

  // epilogue: D col = lane&15, row = (lane>>4)*4 + reg (HW-verified mapping)
#pragma unroll
  for (int ni = 0; ni < 4; ++ni) {
    int col = n0 + wn * 64 + ni * 16 + fr;
    float bv = bias[col];
#pragma unroll
    for (int mi = 0; mi < 8; ++mi) {
      int rowbase = m0 + wm * 128 + mi * 16 + g * 4;
      if (MODE == 1) {
#pragma unroll
        for (int j = 0; j < 4; ++j)
          ((float*)Cv)[(size_t)(rowbase + j) * NDIM + col] = acc[mi][ni][j] + bv;
      } else {
        ushort4 o;
        o.x = f2bf(acc[mi][ni][0] + bv);
        o.y = f2bf(acc[mi][ni][1] + bv);
        o.z = f2bf(acc[mi][ni][2] + bv);
        o.w = f2bf(acc[mi][ni][3] + bv);
        if (col < 2048) {
          int tt = col >> 10;           // 0=Q, 1=K
          int hh = (col >> 6) & 15;
          int d = col & 63;
          int b = rowbase >> 12;
          int s = rowbase & 4095;
          size_t off = ((((size_t)tt * BB + b) * HH + hh) * 64 + d) * SS + s;
          *(ushort4*)&qT[off] = o;     // 4 consecutive s
        } else {
          int c = col - 2048;
          vbuf[(size_t)(rowbase + 0) * HIDD + c] = o.x;
          vbuf[(size_t)(rowbase + 1) * HIDD + c] = o.y;
          vbuf[(size_t)(rowbase + 2) * HIDD + c] = o.z;
          vbuf[(size_t)(rowbase + 3) * HIDD + c] = o.w;
        }
      }
    }
  }
}

// ------- gram eighth + fused sumsq partials -------
// grid (64 bh, 8 p): 512 s per block. 3-buffer counted-vmcnt staging.
// NO runtime-indexed register arrays (rule #20): K-row sumsq uses static ni
// with wave-uniform (ni == w) predicate.
// Partials to d_out scratch: Wp8[bh*8+p][64][64] f32, sq8/sk8[bh*8+p][64].
__global__ __launch_bounds__(256) void k_gram(const ushort* __restrict__ qT,
                                              float* __restrict__ Wp8,
                                              float* __restrict__ sq8,
                                              float* __restrict__ sk8) {
  __shared__ ushort Qs[3][64 * 64];
  __shared__ ushort Ks[3][64 * 64];
  const int bh = blockIdx.x, p = blockIdx.y;
  const ushort* Qp = qT + (size_t)bh * 64 * SS + p * 512;
  const ushort* Kp = qT + (size_t)(BB * HH + bh) * 64 * SS + p * 512;
  const int t = threadIdx.x;
  const int lane = t & 63, w = t >> 6;
  const int fr = lane & 15, g = lane >> 4;
  const int rsub = lane >> 3;
  const int gcol = ((lane & 7) ^ rsub) * 8;

  f32x4_t acc[4] = {};
  float sqa = 0.f, ska = 0.f;

#define STGG(b_, sc_)                                                       \
  _Pragma("unroll") for (int i = 0; i < 2; ++i) {                           \
    int rg = w * 2 + i;                                                     \
    int row = rg * 8 + rsub;                                                \
    gload16(&Qp[(size_t)row * SS + (sc_) * 64 + gcol], &Qs[b_][rg * 512]);  \
    gload16(&Kp[(size_t)row * SS + (sc_) * 64 + gcol], &Ks[b_][rg * 512]);  \
  }

#define GCOMP(bc)                                                           \
  {                                                                         \
    bf16x8_t af[2], bq[4][2];                                               \
    _Pragma("unroll") for (int kk = 0; kk < 2; ++kk) {                      \
      int r = w * 16 + fr;                                                  \
      af[kk] = *(const bf16x8_t*)&Qs[bc][r * 64 + (((kk * 4 + g) ^ (r & 7)) * 8)]; \
    }                                                                       \
    _Pragma("unroll") for (int ni = 0; ni < 4; ++ni)                        \
    _Pragma("unroll") for (int kk = 0; kk < 2; ++kk) {                      \
      int r2 = ni * 16 + fr;                                                \
      bq[ni][kk] = *(const bf16x8_t*)&Ks[bc][r2 * 64 + (((kk * 4 + g) ^ (r2 & 7)) * 8)]; \
    }                                                                       \
    _Pragma("unroll") for (int kk = 0; kk < 2; ++kk)                        \
    _Pragma("unroll") for (int ni = 0; ni < 4; ++ni)                        \
      acc[ni] = __builtin_amdgcn_mfma_f32_16x16x32_bf16(af[kk], bq[ni][kk], acc[ni], 0, 0, 0); \
    _Pragma("unroll") for (int kk = 0; kk < 2; ++kk)                        \
    _Pragma("unroll") for (int e = 0; e < 8; ++e) {                         \
      float fq = bf2f((ushort)af[kk][e]);                                   \
      sqa += fq * fq;                                                       \
    }                                                                       \
    _Pragma("unroll") for (int ni = 0; ni < 4; ++ni)                        \
      if (ni == w)                                                          \
        _Pragma("unroll") for (int kk = 0; kk < 2; ++kk)                    \
        _Pragma("unroll") for (int e = 0; e < 8; ++e) {                     \
          float fk = bf2f((ushort)bq[ni][kk][e]);                           \
          ska += fk * fk;                                                   \
        }                                                                   \
  }

#define GWAIT(n_)                                                           \
  asm volatile("s_waitcnt vmcnt(" #n_ ")" ::: "memory");                    \
  __builtin_amdgcn_s_barrier();                                             \
  __builtin_amdgcn_sched_barrier(0);

  STGG(0, 0);
  STGG(1, 1);
  for (int sc = 0; sc < 6; ++sc) {
    STGG((sc + 2) % 3, sc + 2);
    GWAIT(8);
    GCOMP(sc % 3);
    __builtin_amdgcn_s_barrier();
  }
  GWAIT(4); GCOMP(0); __builtin_amdgcn_s_barrier();  // sc=6 -> buf 0
  GWAIT(0); GCOMP(1);                                 // sc=7 -> buf 1
#undef STGG
#undef GCOMP
#undef GWAIT

  // reduce per-row sumsq over the 4 g-lanes; write partials
  sqa += __shfl_xor(sqa, 16, 64); sqa += __shfl_xor(sqa, 32, 64);
  ska += __shfl_xor(ska, 16, 64); ska += __shfl_xor(ska, 32, 64);
  const int bp = bh * 8 + p;
  if (g == 0) {
    sq8[bp * 64 + w * 16 + fr] = sqa;
    sk8[bp * 64 + w * 16 + fr] = ska;
  }
  float* wp = Wp8 + (size_t)bp * 4096;
#pragma unroll
  for (int ni = 0; ni < 4; ++ni)
#pragma unroll
    for (int j = 0; j < 4; ++j)
      wp[(w * 16 + g * 4 + j) * 64 + ni * 16 + fr] = acc[ni][j];
}

// ------- smx: combine partials, scale, softmax -> bf16 attnb[bh][64][72] ----
__global__ __launch_bounds__(256) void k_smx(const float* __restrict__ Wp8,
                                             const float* __restrict__ sq8,
                                             const float* __restrict__ sk8,
                                             const float* __restrict__ temperature,
                                             ushort* __restrict__ attnb) {
  __shared__ float attnf[64][65];
  __shared__ float iqL[64], ikL[64], invs[64];
  const int bh = blockIdx.x, h = bh & 15;
  const int t = threadIdx.x;
  if (t < 64) {
    float sq = 0.f, sk = 0.f;
#pragma unroll
    for (int p = 0; p < 8; ++p) {
      sq += sq8[(bh * 8 + p) * 64 + t];
      sk += sk8[(bh * 8 + p) * 64 + t];
    }
    iqL[t] = 1.0f / fmaxf(sqrtf(sq), 1e-12f);
    ikL[t] = 1.0f / fmaxf(sqrtf(sk), 1e-12f);
  }
  __syncthreads();
  float tscale = temperature[h] * (1.0f / 32.0f);
  for (int idx = t; idx < 4096; idx += 256) {
    int d = idx >> 6, e = idx & 63;
    float s = 0.f;
#pragma unroll
    for (int p = 0; p < 8; ++p) s += Wp8[(size_t)(bh * 8 + p) * 4096 + idx];
    attnf[d][e] = s * iqL[d] * ikL[e] * tscale;
  }
  __syncthreads();
  if (t < 64) {
    float m = -1e30f;
#pragma unroll 8
    for (int e = 0; e < 64; ++e) m = fmaxf(m, attnf[t][e]);
    float sum = 0.f;
#pragma unroll 8
    for (int e = 0; e < 64; ++e) {
      float v = __expf(attnf[t][e] - m);
      attnf[t][e] = v;
      sum += v;
    }
    invs[t] = 1.0f / sum;
  }
  __syncthreads();
  for (int idx = t; idx < 4096; idx += 256) {
    int d = idx >> 6, e = idx & 63;
    attnb[(size_t)bh * 4608 + d * 72 + e] = f2bf(attnf[d][e] * invs[d]);
  }
}

// ---------------- PV (MFMA): out[s][d] = sum_e V[s,e] * attn[d,e] ----------
// grid (64 bh, 8 p): 512 s-rows per block, 3-buffer counted-vmcnt staging.
__global__ __launch_bounds__(256) void k_pv(const ushort* __restrict__ vbuf,
                                            const ushort* __restrict__ attnb,
                                            ushort* __restrict__ attnout) {
  __shared__ ushort Vs[3][64 * 64];
  const int bh = blockIdx.x, p = blockIdx.y;
  const int b = bh >> 4, h = bh & 15;
  const int t = threadIdx.x;
  const int lane = t & 63, w = t >> 6;
  const int fr = lane & 15, g = lane >> 4;
  const int rsub = lane >> 3;
  const int gcol = ((lane & 7) ^ rsub) * 8;

  // B-frags straight from global attnb (L2-hot)
  bf16x8_t bfg[4][2];
#pragma unroll
  for (int ni = 0; ni < 4; ++ni)
#pragma unroll
    for (int kk = 0; kk < 2; ++kk)
      bfg[ni][kk] = *(const bf16x8_t*)&attnb[(size_t)bh * 4608 + (ni * 16 + fr) * 72 + (kk * 4 + g) * 8];

  const ushort* vb = vbuf + (size_t)(b * SS + p * 512) * HIDD + h * 64;
  ushort* ob = attnout + (size_t)(b * SS + p * 512) * HIDD + h * 64;

#define STGV(b_, c_)                                                        \
  _Pragma("unroll") for (int i = 0; i < 2; ++i) {                           \
    int rg = w * 2 + i;                                                     \
    int row = rg * 8 + rsub;                                                \
    gload16(&vb[(size_t)((c_) * 64 + row) * HIDD + gcol], &Vs[b_][rg * 512]); \
  }

#define PCOMP(bc, c_)                                                       \
  {                                                                         \
    f32x4_t acc[4] = {};                                                    \
    _Pragma("unroll") for (int kk = 0; kk < 2; ++kk) {                      \
      int r = w * 16 + fr;                                                  \
      bf16x8_t af = *(const bf16x8_t*)&Vs[bc][r * 64 + (((kk * 4 + g) ^ (r & 7)) * 8)]; \
      _Pragma("unroll") for (int ni = 0; ni < 4; ++ni)                      \
        acc[ni] = __builtin_amdgcn_mfma_f32_16x16x32_bf16(af, bfg[ni][kk], acc[ni], 0, 0, 0); \
    }                                                                       \
    _Pragma("unroll") for (int ni = 0; ni < 4; ++ni)                        \
    _Pragma("unroll") for (int j = 0; j < 4; ++j)                           \
      ob[(size_t)((c_) * 64 + w * 16 + g * 4 + j) * HIDD + ni * 16 + fr] = f2bf(acc[ni][j]); \
  }

#define PWAIT(n_)                                                           \
  asm volatile("s_waitcnt vmcnt(" #n_ ")" ::: "memory");                    \
  __builtin_amdgcn_s_barrier();                                             \
  __builtin_amdgcn_sched_barrier(0);

  STGV(0, 0);
  STGV(1, 1);
  for (int c = 0; c < 6; ++c) {
    STGV((c + 2) % 3, c + 2);
    PWAIT(4);
    PCOMP(c % 3, c);
    __builtin_amdgcn_s_barrier();
  }
  PWAIT(2); PCOMP(0, 6); __builtin_amdgcn_s_barrier();
  PWAIT(0); PCOMP(1, 7);
#undef STGV
#undef PCOMP
#undef PWAIT
}

extern "C" void kernel_launch(void* const* d_in, const int* in_sizes, int n_in,
                              void* d_out, int out_size, void* d_ws, size_t ws_size,
                              hipStream_t stream) {
  const float* x = (const float*)d_in[0];
  const float* Wqkv = (const float*)d_in[1];
  const float* bqkv = (const float*)d_in[2];
  const float* Wz = (const float*)d_in[3];
  const float* bz = (const float*)d_in[4];
  const float* temperature = (const float*)d_in[5];

  char* ws = (char*)d_ws;
  ushort* xb    = (ushort*)(ws + 0);           // 33,554,432 (alias: attnout)
  ushort* wqb   = (ushort*)(ws + 33554432);    // 6,291,456
  ushort* wzb   = (ushort*)(ws + 39845888);    // 2,097,152
  ushort* vbuf  = (ushort*)(ws + 41943040);    // 33,554,432
  ushort* qkvT  = (ushort*)(ws + 75497472);    // 67,108,864  [t][b][h][d][s]
  ushort* attnout = xb;  // x is dead after QKV GEMM

  // scratch inside d_out (64 MB, fully overwritten by GEMM2 at the end):
  float* dsc = (float*)d_out;
  float* Wp8 = dsc;                        // 2,097,152 floats (8 MB)
  float* sq8 = dsc + 2097152;              // 32,768 floats
  float* sk8 = dsc + 2097152 + 32768;      // 32,768 floats
  ushort* attnb = (ushort*)(dsc + 2097152 + 65536);  // 294,912 ushorts

  // 1) converts
  k_f2bf<<<dim3(16384), dim3(256), 0, stream>>>(x, xb, (MM * HIDD) / 4);
  k_f2bf<<<dim3(3072), dim3(256), 0, stream>>>(Wqkv, wqb, (NQKV * HIDD) / 4);
  k_f2bf<<<dim3(1024), dim3(256), 0, stream>>>(Wz, wzb, (HIDD * HIDD) / 4);

  // 2) QKV GEMM -> QT/KT transposed + V natural
  k_gemm8p<2, MM, NQKV, HIDD><<<dim3(MM / 256, NQKV / 256), dim3(512), 0, stream>>>(
      xb, wqb, bqkv, nullptr, qkvT, vbuf);

  // 3) gram eighths (+fused sumsq) -> combine+softmax
  k_gram<<<dim3(64, 8), dim3(256), 0, stream>>>(qkvT, Wp8, sq8, sk8);
  k_smx<<<dim3(64), dim3(256), 0, stream>>>(Wp8, sq8, sk8, temperature, attnb);

  // 4) PV (MFMA)
  k_pv<<<dim3(64, 8), dim3(256), 0, stream>>>(vbuf, attnb, attnout);

  // 5) output GEMM -> d_out fp32 (overwrites the scratch)
  k_gemm8p<1, MM, HIDD, HIDD><<<dim3(MM / 256, HIDD / 256), dim3(512), 0, stream>>>(
      attnout, wzb, bz, d_out, nullptr, nullptr);
}